// Round 9
// baseline (151.497 us; speedup 1.0000x reference)
//
#include <hip/hip_runtime.h>
#include <hip/hip_bf16.h>

#define N_  32
#define C_  64
#define T_  300
#define V_  25
#define TV  (T_*V_)        // 7500
#define CTV (C_*TV)        // 480000
#define NELEM (N_*CTV)     // 15360000
#define CNTF 240000.0f

typedef float f32x4 __attribute__((ext_vector_type(4)));
typedef short bf16x8 __attribute__((ext_vector_type(8)));
typedef short s4v __attribute__((ext_vector_type(4)));
typedef short s8v __attribute__((ext_vector_type(8)));

__device__ __forceinline__ unsigned short f2bf(float f) {
    unsigned u = __float_as_uint(f);
    unsigned r = u + 0x7fffu + ((u >> 16) & 1u);
    return (unsigned short)(r >> 16);
}
__device__ __forceinline__ float bf2f(unsigned short u) {
    return __uint_as_float(((unsigned)u) << 16);
}
// HW packed f32->bf16 (RNE)
__device__ __forceinline__ unsigned cvt_pk(float lo, float hi) {
    unsigned r;
    asm("v_cvt_pk_bf16_f32 %0, %1, %2" : "=v"(r) : "v"(lo), "v"(hi));
    return r;
}

// ---------------------------------------------------------------------------
// k_prep: one-time weight conversion to bf16 in MFMA A-frag friendly layouts.
// ---------------------------------------------------------------------------
__global__ __launch_bounds__(256) void k_prep(
    const float* __restrict__ conv_w, const float* __restrict__ tw,
    unsigned short* __restrict__ w2b, unsigned short* __restrict__ twb)
{
    int tid = blockIdx.x*256 + threadIdx.x;
    for (int e = tid; e < 20480; e += 8192) {
        int ks = e >> 11, c = (e >> 5) & 63, kk = e & 31;
        w2b[e] = f2bf(conv_w[(((ks>>1)*64 + c)*64) + (ks&1)*32 + kk]);
    }
    for (int e = tid; e < 36864; e += 8192) {
        int gi = e >> 11, c = (e >> 5) & 63, kk = e & 31;
        int dt = gi >> 1, ks = gi & 1;
        twb[e] = f2bf(tw[(c*64 + 32*ks + kk)*9 + dt]);
    }
}

// ---------------------------------------------------------------------------
// k_gcn: EXACT round-7 version (known-pass). grid (30, 32), 10 t per block.
// ---------------------------------------------------------------------------
__global__ __launch_bounds__(256) void k_gcn(
    const float* __restrict__ x, const float* __restrict__ A,
    const float* __restrict__ B, const float* __restrict__ lamda,
    const unsigned short* __restrict__ w2b, const float* __restrict__ conv_b,
    unsigned short* __restrict__ gout, float* __restrict__ stats3)
{
    __shared__ unsigned short ash[5*32*40];   // aeff^T [k][w][v], pads zero
    __shared__ unsigned short zsh[32*328];    // [w][j]
    __shared__ float csum[160];
    __shared__ float sbc[320];

    const int tb = blockIdx.x, n = blockIdx.y;
    const int t0 = tb*10;
    const int tid = threadIdx.x;
    const int lane = tid & 63, wv = tid >> 6;
    const int lg = lane >> 4, lr = lane & 15;
    const int crow = lr + 16*wv;
    const int cbase = 16*wv + 4*lg;

    bf16x8 wfrag[10];
    #pragma unroll
    for (int ks = 0; ks < 10; ++ks)
        wfrag[ks] = *(const bf16x8*)&w2b[(ks*64 + crow)*32 + 8*lg];

    const float lam = lamda[0];
    // zero-prefill ash (covers pads), then fill from contiguous A/B reads
    {
        s8v z8 = {0,0,0,0,0,0,0,0};
        for (int e = tid; e < 800; e += 256) *(s8v*)&ash[e*8] = z8;
    }
    for (int e = tid; e < 320; e += 256) sbc[e] = conv_b[e];
    __syncthreads();
    for (int e = tid; e < 3125; e += 256) {
        int k = e / 625, r = e - k*625;
        int v = r / 25, w = r - v*25;
        float val = (k < 3) ? A[e] : lam * B[((n<<1) + (k-3))*625 + r];
        ash[k*1280 + w*40 + v] = f2bf(val);
    }
    __syncthreads();
    for (int e = tid; e < 160; e += 256) {
        int k = e / 32, w = e % 32;
        float s = 0.f;
        for (int v = 0; v < 25; ++v) s += bf2f(ash[k*1280 + w*40 + v]);
        csum[e] = s;
    }
    __syncthreads();

    float bs0[4], bs1[4];
    #pragma unroll
    for (int r = 0; r < 4; ++r) {
        float s0 = 0.f, s1 = 0.f;
        #pragma unroll
        for (int k = 0; k < 5; ++k) {
            float cb = sbc[k*64 + cbase + r];
            s0 += cb * csum[k*32 + lr];
            s1 += cb * csum[k*32 + lr + 16];
        }
        bs0[r] = s0; bs1[r] = s1;
    }

    float sacc[4] = {0,0,0,0}, qacc[4] = {0,0,0,0};

    const float* xrow = x + n*CTV + crow*TV + t0*V_;
    float xf[8];
    #pragma unroll
    for (int i = 0; i < 8; ++i) { int v = 8*lg + i; xf[i] = (v < 25) ? xrow[v] : 0.f; }

    for (int tl = 0; tl < 10; ++tl) {
        union { bf16x8 v; unsigned u[4]; } xu;
        #pragma unroll
        for (int p = 0; p < 4; ++p) xu.u[p] = cvt_pk(xf[2*p], xf[2*p+1]);
        bf16x8 xfrag = xu.v;
        if (tl < 9) {
            const float* xn = xrow + (tl+1)*V_;
            #pragma unroll
            for (int i = 0; i < 8; ++i) { int v = 8*lg + i; xf[i] = (v < 25) ? xn[v] : 0.f; }
        }
        // step 1: z tiles -> zsh (packed via cvt_pk)
        #pragma unroll
        for (int k = 0; k < 5; ++k)
        #pragma unroll
        for (int nt = 0; nt < 2; ++nt) {
            bf16x8 bfrag = *(const bf16x8*)&ash[k*1280 + (lr + 16*nt)*40 + 8*lg];
            f32x4 z = {0.f,0.f,0.f,0.f};
            z = __builtin_amdgcn_mfma_f32_16x16x32_bf16(xfrag, bfrag, z, 0, 0, 0);
            uint2 zz;
            zz.x = cvt_pk(z[0], z[1]);
            zz.y = cvt_pk(z[2], z[3]);
            *(uint2*)&zsh[(lr + 16*nt)*328 + k*64 + 16*wv + 4*lg] = zz;
        }
        __syncthreads();
        // step 2: g = W2 @ z
        f32x4 acc0 = {0.f,0.f,0.f,0.f}, acc1 = {0.f,0.f,0.f,0.f};
        #pragma unroll
        for (int ks = 0; ks < 10; ++ks) {
            bf16x8 b0 = *(const bf16x8*)&zsh[lr*328 + 32*ks + 8*lg];
            bf16x8 b1 = *(const bf16x8*)&zsh[(lr+16)*328 + 32*ks + 8*lg];
            acc0 = __builtin_amdgcn_mfma_f32_16x16x32_bf16(wfrag[ks], b0, acc0, 0, 0, 0);
            acc1 = __builtin_amdgcn_mfma_f32_16x16x32_bf16(wfrag[ks], b1, acc1, 0, 0, 0);
        }
        // epilogue: bias, stats, direct global stores
        float v0a[4], v1a[4];
        #pragma unroll
        for (int r = 0; r < 4; ++r) {
            v0a[r] = acc0[r] + bs0[r];
            v1a[r] = acc1[r] + bs1[r];
            sacc[r] += v0a[r] + (lr < 9 ? v1a[r] : 0.f);
            qacc[r] += v0a[r]*v0a[r] + (lr < 9 ? v1a[r]*v1a[r] : 0.f);
        }
        unsigned short* grow = gout + (size_t)(n*300 + t0 + tl)*1600;
        uint2 g0, g1;
        g0.x = cvt_pk(v0a[0], v0a[1]); g0.y = cvt_pk(v0a[2], v0a[3]);
        g1.x = cvt_pk(v1a[0], v1a[1]); g1.y = cvt_pk(v1a[2], v1a[3]);
        *(uint2*)&grow[lr*64 + cbase] = g0;
        if (lr < 9) *(uint2*)&grow[(lr+16)*64 + cbase] = g1;
        __syncthreads();
    }

    #pragma unroll
    for (int r = 0; r < 4; ++r) {
        float s = sacc[r], q = qacc[r];
        s += __shfl_xor(s, 1); s += __shfl_xor(s, 2);
        s += __shfl_xor(s, 4); s += __shfl_xor(s, 8);
        q += __shfl_xor(q, 1); q += __shfl_xor(q, 2);
        q += __shfl_xor(q, 4); q += __shfl_xor(q, 8);
        if (lr == 0) {
            stats3[(n*30 + tb)*128 + cbase + r] = s;
            stats3[(n*30 + tb)*128 + 64 + cbase + r] = q;
        }
    }
}

// ---------------------------------------------------------------------------
// k_fin: reduce per-block stats -> BN scale/shift. grid 64.
// ---------------------------------------------------------------------------
__global__ __launch_bounds__(256) void k_fin(
    const float* __restrict__ src, int count, float* __restrict__ sbo,
    const float* __restrict__ gma, const float* __restrict__ bta)
{
    const int c = blockIdx.x, tid = threadIdx.x;
    float s = 0.f, q = 0.f;
    for (int b = tid; b < count; b += 256) {
        s += src[b*128 + c];
        q += src[b*128 + 64 + c];
    }
    #pragma unroll
    for (int m = 1; m < 64; m <<= 1) { s += __shfl_xor(s, m); q += __shfl_xor(q, m); }
    __shared__ float rs[4], rq[4];
    if ((tid & 63) == 0) { rs[tid>>6] = s; rq[tid>>6] = q; }
    __syncthreads();
    if (tid == 0) {
        s = rs[0]+rs[1]+rs[2]+rs[3]; q = rq[0]+rq[1]+rq[2]+rq[3];
        float mean = s / CNTF, var = q / CNTF - mean*mean;
        float sc = gma[c] * rsqrtf(var + 1e-5f);
        sbo[c] = sc;
        sbo[64 + c] = bta[c] - mean*sc;
    }
}

// ---------------------------------------------------------------------------
// k_tcn v4 (fresh rewrite): grid (19,32), 512 threads, TBLK=16 t per block.
// Stage p = relu(bn1(g)) rows R = tau*25 + w, tau in [0,24) <-> t = t0-4+tau,
// row stride 40 shorts (32 used per i-half). Two ks passes over i.
// Wave wvi: ct = wvi&3 (channel tile), ch = wvi>>2 (col half).
// Output col = tlo*25 + w in [0,400); 25 tiles of 16; ch0: 0..12, ch1: 13..24.
// Epilogue: stats partials per (block,ch); transpose via bf16 hbuf[64][408].
// ---------------------------------------------------------------------------
__global__ __launch_bounds__(512, 4) void k_tcn(
    const unsigned short* __restrict__ gin, const float* __restrict__ sb,
    const unsigned short* __restrict__ twb, const float* __restrict__ tb,
    unsigned short* __restrict__ hout, float* __restrict__ stats4)
{
    __shared__ unsigned short lds[26112];   // stage 600*40=24000; hbuf 64*408=26112
    __shared__ float sbs[128];

    const int n = blockIdx.y, tt = blockIdx.x, t0 = tt*16;
    const int tid = threadIdx.x;
    const int lane = tid & 63, wvi = tid >> 6;
    const int lg = lane >> 4, lr = lane & 15;
    const int ct = wvi & 3, ch = wvi >> 2;
    const int cA = ct*16 + lr;              // A-frag row (output channel m=lr)
    const int cbase = ct*16 + 4*lg;         // D row base

    for (int e = tid; e < 128; e += 512) sbs[e] = sb[e];

    f32x4 acc[13];
    #pragma unroll
    for (int i = 0; i < 13; ++i) acc[i] = (f32x4){0.f,0.f,0.f,0.f};

    for (int ks = 0; ks < 2; ++ks) {
        // A-frags for this i-half: tw[c=cA][i_in=32ks+8lg+j][dt]
        bf16x8 af[9];
        #pragma unroll
        for (int dt = 0; dt < 9; ++dt)
            af[dt] = *(const bf16x8*)&twb[((2*dt + ks)*64 + cA)*32 + 8*lg];

        __syncthreads();   // prev-pass LDS reads done; sbs visible (ks=0)
        for (int e = tid; e < 2400; e += 512) {
            int row = e >> 2, q = e & 3;    // q: which 8-channel group
            int tau = row / 25, w = row % 25;
            int tg = t0 - 4 + tau;
            int i8 = 32*ks + q*8;
            uint4 pk4 = {0,0,0,0};
            if (tg >= 0 && tg < 300) {
                s8v raw = *(const s8v*)&gin[(size_t)((n*300 + tg)*25 + w)*64 + i8];
                float f[8];
                #pragma unroll
                for (int j = 0; j < 8; ++j)
                    f[j] = fmaxf(fmaf(bf2f((unsigned short)raw[j]), sbs[i8+j], sbs[64+i8+j]), 0.f);
                pk4.x = cvt_pk(f[0], f[1]);
                pk4.y = cvt_pk(f[2], f[3]);
                pk4.z = cvt_pk(f[4], f[5]);
                pk4.w = cvt_pk(f[6], f[7]);
            }
            *(uint4*)&lds[row*40 + q*8] = pk4;
        }
        __syncthreads();

        #pragma unroll
        for (int i = 0; i < 13; ++i) {
            int nt = 13*ch + i;
            if (nt < 25) {                  // wave-uniform
                int col = 16*nt + lr;       // output (tlo, w) index
                #pragma unroll
                for (int dt = 0; dt < 9; ++dt) {
                    bf16x8 b = *(const bf16x8*)&lds[(col + 25*dt)*40 + 8*lg];
                    acc[i] = __builtin_amdgcn_mfma_f32_16x16x32_bf16(af[dt], b, acc[i], 0, 0, 0);
                }
            }
        }
    }

    const int lim = min(400, (300 - t0)*25);
    float tbc[4];
    #pragma unroll
    for (int r = 0; r < 4; ++r) tbc[r] = tb[cbase + r];

    // stats partials from accumulators (per block, per col-half)
    float sacc[4] = {0,0,0,0}, qacc[4] = {0,0,0,0};
    #pragma unroll
    for (int i = 0; i < 13; ++i) {
        int nt = 13*ch + i;
        if (nt < 25) {
            int col = 16*nt + lr;
            if (col < lim) {
                #pragma unroll
                for (int r = 0; r < 4; ++r) {
                    float v = acc[i][r] + tbc[r];
                    sacc[r] += v; qacc[r] += v*v;
                }
            }
        }
    }
    #pragma unroll
    for (int r = 0; r < 4; ++r) {
        float s = sacc[r], q = qacc[r];
        s += __shfl_xor(s, 1); s += __shfl_xor(s, 2);
        s += __shfl_xor(s, 4); s += __shfl_xor(s, 8);
        q += __shfl_xor(q, 1); q += __shfl_xor(q, 2);
        q += __shfl_xor(q, 4); q += __shfl_xor(q, 8);
        if (lr == 0) {
            float* dst = stats4 + (size_t)((n*19 + tt)*2 + ch)*128;
            dst[cbase + r] = s;
            dst[64 + cbase + r] = q;
        }
    }

    // transpose via bf16 hbuf[64][408] aliased onto lds, then coalesced writes
    __syncthreads();
    unsigned short* hbuf = lds;
    #pragma unroll
    for (int i = 0; i < 13; ++i) {
        int nt = 13*ch + i;
        if (nt < 25) {
            int col = 16*nt + lr;
            #pragma unroll
            for (int r = 0; r < 4; ++r)
                hbuf[(cbase + r)*408 + col] = f2bf(acc[i][r] + tbc[r]);
        }
    }
    __syncthreads();
    for (int e = tid; e < 6400; e += 512) {
        int row = e / 100, c4 = (e % 100)*4;
        if (c4 < lim) {
            s4v o = *(const s4v*)&hbuf[row*408 + c4];
            *(s4v*)&hout[((size_t)(n*64 + row)*300 + t0)*25 + c4] = o;
        }
    }
}

// ---------------------------------------------------------------------------
// k_out: out = relu(bn2(h) + x) f32
// ---------------------------------------------------------------------------
__global__ __launch_bounds__(256) void k_out(
    const unsigned short* __restrict__ h, const float* __restrict__ x,
    const float* __restrict__ sb, float* __restrict__ out)
{
    int i4 = blockIdx.x * 256 + threadIdx.x;
    if (i4 >= NELEM/4) return;
    int c = ((i4*4) / TV) & 63;
    float s2 = sb[128 + c], b2 = sb[192 + c];
    s4v hv = *(const s4v*)&h[i4*4];
    float4 xv = ((const float4*)x)[i4];
    float4 o;
    o.x = fmaxf(fmaf(bf2f((unsigned short)hv[0]), s2, b2) + xv.x, 0.f);
    o.y = fmaxf(fmaf(bf2f((unsigned short)hv[1]), s2, b2) + xv.y, 0.f);
    o.z = fmaxf(fmaf(bf2f((unsigned short)hv[2]), s2, b2) + xv.z, 0.f);
    o.w = fmaxf(fmaf(bf2f((unsigned short)hv[3]), s2, b2) + xv.w, 0.f);
    ((float4*)out)[i4] = o;
}

// ---------------------------------------------------------------------------
extern "C" void kernel_launch(void* const* d_in, const int* in_sizes, int n_in,
                              void* d_out, int out_size, void* d_ws, size_t ws_size,
                              hipStream_t stream)
{
    const float* x      = (const float*)d_in[0];
    const float* A      = (const float*)d_in[1];
    const float* B      = (const float*)d_in[2];
    const float* lamda  = (const float*)d_in[3];
    const float* conv_w = (const float*)d_in[4];
    const float* conv_b = (const float*)d_in[5];
    const float* bn1_g  = (const float*)d_in[6];
    const float* bn1_b  = (const float*)d_in[7];
    const float* tcn_w  = (const float*)d_in[8];
    const float* tcn_b  = (const float*)d_in[9];
    const float* bn2_g  = (const float*)d_in[10];
    const float* bn2_b  = (const float*)d_in[11];

    unsigned short* g = (unsigned short*)d_ws;          // NELEM bf16
    unsigned short* h = g + NELEM;                      // NELEM bf16
    float* stats3 = (float*)(h + NELEM);                // 960*128
    float* stats4 = stats3 + 960*128;                   // 1216*128
    float* sb     = stats4 + 1216*128;                  // 256
    unsigned short* w2b = (unsigned short*)(sb + 256);  // 20480
    unsigned short* twb = w2b + 20480;                  // 36864

    k_prep<<<32, 256, 0, stream>>>(conv_w, tcn_w, w2b, twb);
    k_gcn<<<dim3(30, N_), 256, 0, stream>>>(x, A, B, lamda, w2b, conv_b, g, stats3);
    k_fin<<<64, 256, 0, stream>>>(stats3, 960, sb, bn1_g, bn1_b);
    k_tcn<<<dim3(19, N_), 512, 0, stream>>>(g, sb, twb, tcn_b, h, stats4);
    k_fin<<<64, 256, 0, stream>>>(stats4, 1216, sb + 128, bn2_g, bn2_b);
    k_out<<<NELEM/4/256, 256, 0, stream>>>(h, x, sb, (float*)d_out);
}

// Round 10
// 134.626 us; speedup vs baseline: 1.1253x; 1.1253x over previous
//
#include <hip/hip_runtime.h>
#include <hip/hip_bf16.h>

#define N_  32
#define C_  64
#define T_  300
#define V_  25
#define TV  (T_*V_)        // 7500
#define CTV (C_*TV)        // 480000
#define NELEM (N_*CTV)     // 15360000
#define CNTF 240000.0f
#define PROWS 7788         // 128 front pad + 7500 + 160 back pad

typedef float f32x4 __attribute__((ext_vector_type(4)));
typedef short bf16x8 __attribute__((ext_vector_type(8)));
typedef short s4v __attribute__((ext_vector_type(4)));
typedef short s8v __attribute__((ext_vector_type(8)));

__device__ __forceinline__ unsigned short f2bf(float f) {
    unsigned u = __float_as_uint(f);
    unsigned r = u + 0x7fffu + ((u >> 16) & 1u);
    return (unsigned short)(r >> 16);
}
__device__ __forceinline__ float bf2f(unsigned short u) {
    return __uint_as_float(((unsigned)u) << 16);
}
// HW packed f32->bf16 (RNE)
__device__ __forceinline__ unsigned cvt_pk(float lo, float hi) {
    unsigned r;
    asm("v_cvt_pk_bf16_f32 %0, %1, %2" : "=v"(r) : "v"(lo), "v"(hi));
    return r;
}

// ---------------------------------------------------------------------------
// k_prep: one-time weight conversion to bf16 in MFMA A-frag friendly layouts.
// ---------------------------------------------------------------------------
__global__ __launch_bounds__(256) void k_prep(
    const float* __restrict__ conv_w, const float* __restrict__ tw,
    unsigned short* __restrict__ w2b, unsigned short* __restrict__ twb)
{
    int tid = blockIdx.x*256 + threadIdx.x;
    for (int e = tid; e < 20480; e += 8192) {
        int ks = e >> 11, c = (e >> 5) & 63, kk = e & 31;
        w2b[e] = f2bf(conv_w[(((ks>>1)*64 + c)*64) + (ks&1)*32 + kk]);
    }
    for (int e = tid; e < 36864; e += 8192) {
        int gi = e >> 11, c = (e >> 5) & 63, kk = e & 31;
        int dt = gi >> 1, ks = gi & 1;
        twb[e] = f2bf(tw[(c*64 + 32*ks + kk)*9 + dt]);
    }
}

// ---------------------------------------------------------------------------
// k_gcn: EXACT round-7 version (known-pass). grid (30, 32), 10 t per block.
// ---------------------------------------------------------------------------
__global__ __launch_bounds__(256) void k_gcn(
    const float* __restrict__ x, const float* __restrict__ A,
    const float* __restrict__ B, const float* __restrict__ lamda,
    const unsigned short* __restrict__ w2b, const float* __restrict__ conv_b,
    unsigned short* __restrict__ gout, float* __restrict__ stats3)
{
    __shared__ unsigned short ash[5*32*40];   // aeff^T [k][w][v], pads zero
    __shared__ unsigned short zsh[32*328];    // [w][j]
    __shared__ float csum[160];
    __shared__ float sbc[320];

    const int tb = blockIdx.x, n = blockIdx.y;
    const int t0 = tb*10;
    const int tid = threadIdx.x;
    const int lane = tid & 63, wv = tid >> 6;
    const int lg = lane >> 4, lr = lane & 15;
    const int crow = lr + 16*wv;
    const int cbase = 16*wv + 4*lg;

    bf16x8 wfrag[10];
    #pragma unroll
    for (int ks = 0; ks < 10; ++ks)
        wfrag[ks] = *(const bf16x8*)&w2b[(ks*64 + crow)*32 + 8*lg];

    const float lam = lamda[0];
    {
        s8v z8 = {0,0,0,0,0,0,0,0};
        for (int e = tid; e < 800; e += 256) *(s8v*)&ash[e*8] = z8;
    }
    for (int e = tid; e < 320; e += 256) sbc[e] = conv_b[e];
    __syncthreads();
    for (int e = tid; e < 3125; e += 256) {
        int k = e / 625, r = e - k*625;
        int v = r / 25, w = r - v*25;
        float val = (k < 3) ? A[e] : lam * B[((n<<1) + (k-3))*625 + r];
        ash[k*1280 + w*40 + v] = f2bf(val);
    }
    __syncthreads();
    for (int e = tid; e < 160; e += 256) {
        int k = e / 32, w = e % 32;
        float s = 0.f;
        for (int v = 0; v < 25; ++v) s += bf2f(ash[k*1280 + w*40 + v]);
        csum[e] = s;
    }
    __syncthreads();

    float bs0[4], bs1[4];
    #pragma unroll
    for (int r = 0; r < 4; ++r) {
        float s0 = 0.f, s1 = 0.f;
        #pragma unroll
        for (int k = 0; k < 5; ++k) {
            float cb = sbc[k*64 + cbase + r];
            s0 += cb * csum[k*32 + lr];
            s1 += cb * csum[k*32 + lr + 16];
        }
        bs0[r] = s0; bs1[r] = s1;
    }

    float sacc[4] = {0,0,0,0}, qacc[4] = {0,0,0,0};

    const float* xrow = x + n*CTV + crow*TV + t0*V_;
    float xf[8];
    #pragma unroll
    for (int i = 0; i < 8; ++i) { int v = 8*lg + i; xf[i] = (v < 25) ? xrow[v] : 0.f; }

    for (int tl = 0; tl < 10; ++tl) {
        union { bf16x8 v; unsigned u[4]; } xu;
        #pragma unroll
        for (int p = 0; p < 4; ++p) xu.u[p] = cvt_pk(xf[2*p], xf[2*p+1]);
        bf16x8 xfrag = xu.v;
        if (tl < 9) {
            const float* xn = xrow + (tl+1)*V_;
            #pragma unroll
            for (int i = 0; i < 8; ++i) { int v = 8*lg + i; xf[i] = (v < 25) ? xn[v] : 0.f; }
        }
        #pragma unroll
        for (int k = 0; k < 5; ++k)
        #pragma unroll
        for (int nt = 0; nt < 2; ++nt) {
            bf16x8 bfrag = *(const bf16x8*)&ash[k*1280 + (lr + 16*nt)*40 + 8*lg];
            f32x4 z = {0.f,0.f,0.f,0.f};
            z = __builtin_amdgcn_mfma_f32_16x16x32_bf16(xfrag, bfrag, z, 0, 0, 0);
            uint2 zz;
            zz.x = cvt_pk(z[0], z[1]);
            zz.y = cvt_pk(z[2], z[3]);
            *(uint2*)&zsh[(lr + 16*nt)*328 + k*64 + 16*wv + 4*lg] = zz;
        }
        __syncthreads();
        f32x4 acc0 = {0.f,0.f,0.f,0.f}, acc1 = {0.f,0.f,0.f,0.f};
        #pragma unroll
        for (int ks = 0; ks < 10; ++ks) {
            bf16x8 b0 = *(const bf16x8*)&zsh[lr*328 + 32*ks + 8*lg];
            bf16x8 b1 = *(const bf16x8*)&zsh[(lr+16)*328 + 32*ks + 8*lg];
            acc0 = __builtin_amdgcn_mfma_f32_16x16x32_bf16(wfrag[ks], b0, acc0, 0, 0, 0);
            acc1 = __builtin_amdgcn_mfma_f32_16x16x32_bf16(wfrag[ks], b1, acc1, 0, 0, 0);
        }
        float v0a[4], v1a[4];
        #pragma unroll
        for (int r = 0; r < 4; ++r) {
            v0a[r] = acc0[r] + bs0[r];
            v1a[r] = acc1[r] + bs1[r];
            sacc[r] += v0a[r] + (lr < 9 ? v1a[r] : 0.f);
            qacc[r] += v0a[r]*v0a[r] + (lr < 9 ? v1a[r]*v1a[r] : 0.f);
        }
        unsigned short* grow = gout + (size_t)(n*300 + t0 + tl)*1600;
        uint2 g0, g1;
        g0.x = cvt_pk(v0a[0], v0a[1]); g0.y = cvt_pk(v0a[2], v0a[3]);
        g1.x = cvt_pk(v1a[0], v1a[1]); g1.y = cvt_pk(v1a[2], v1a[3]);
        *(uint2*)&grow[lr*64 + cbase] = g0;
        if (lr < 9) *(uint2*)&grow[(lr+16)*64 + cbase] = g1;
        __syncthreads();
    }

    #pragma unroll
    for (int r = 0; r < 4; ++r) {
        float s = sacc[r], q = qacc[r];
        s += __shfl_xor(s, 1); s += __shfl_xor(s, 2);
        s += __shfl_xor(s, 4); s += __shfl_xor(s, 8);
        q += __shfl_xor(q, 1); q += __shfl_xor(q, 2);
        q += __shfl_xor(q, 4); q += __shfl_xor(q, 8);
        if (lr == 0) {
            stats3[(n*30 + tb)*128 + cbase + r] = s;
            stats3[(n*30 + tb)*128 + 64 + cbase + r] = q;
        }
    }
}

// ---------------------------------------------------------------------------
// k_fin: reduce per-block stats -> BN scale/shift. grid 64.
// ---------------------------------------------------------------------------
__global__ __launch_bounds__(256) void k_fin(
    const float* __restrict__ src, int count, float* __restrict__ sbo,
    const float* __restrict__ gma, const float* __restrict__ bta)
{
    const int c = blockIdx.x, tid = threadIdx.x;
    float s = 0.f, q = 0.f;
    for (int b = tid; b < count; b += 256) {
        s += src[b*128 + c];
        q += src[b*128 + 64 + c];
    }
    #pragma unroll
    for (int m = 1; m < 64; m <<= 1) { s += __shfl_xor(s, m); q += __shfl_xor(q, m); }
    __shared__ float rs[4], rq[4];
    if ((tid & 63) == 0) { rs[tid>>6] = s; rq[tid>>6] = q; }
    __syncthreads();
    if (tid == 0) {
        s = rs[0]+rs[1]+rs[2]+rs[3]; q = rq[0]+rq[1]+rq[2]+rq[3];
        float mean = s / CNTF, var = q / CNTF - mean*mean;
        float sc = gma[c] * rsqrtf(var + 1e-5f);
        sbo[c] = sc;
        sbo[64 + c] = bta[c] - mean*sc;
    }
}

// ---------------------------------------------------------------------------
// k_bn1: p[n][row+128][c] = bf16(relu(bn1(g[n][row][c]))), rows outside
// [0,7500) zeroed (pad). grid 7788 blocks x 256 thr; one 16B chunk/thread.
// ---------------------------------------------------------------------------
__global__ __launch_bounds__(256) void k_bn1(
    const unsigned short* __restrict__ g, const float* __restrict__ sb,
    unsigned short* __restrict__ p)
{
    __shared__ float sbs[128];
    if (threadIdx.x < 128) sbs[threadIdx.x] = sb[threadIdx.x];
    __syncthreads();
    int idx = blockIdx.x*256 + threadIdx.x;      // < 32*7788*8 = 1993728
    int n = idx / (PROWS*8);
    int rem = idx - n*(PROWS*8);
    int row = (rem >> 3) - 128;                  // [-128, 7660)
    int q8 = (rem & 7) * 8;
    uint4 out4 = {0,0,0,0};
    if (row >= 0 && row < 7500) {
        s8v raw = *(const s8v*)&g[((size_t)n*7500 + row)*64 + q8];
        float f[8];
        #pragma unroll
        for (int j = 0; j < 8; ++j)
            f[j] = fmaxf(fmaf(bf2f((unsigned short)raw[j]), sbs[q8+j], sbs[64+q8+j]), 0.f);
        out4.x = cvt_pk(f[0], f[1]); out4.y = cvt_pk(f[2], f[3]);
        out4.z = cvt_pk(f[4], f[5]); out4.w = cvt_pk(f[6], f[7]);
    }
    *(uint4*)&p[(size_t)idx*8] = out4;
}

// ---------------------------------------------------------------------------
// k_tcn v5: grid (59,32), 256 thr = 4 waves (wave = c-tile ct).
// Global col index j = t*25+w; dt shift = j + 25(dt-4); pads absorb edges.
// Stage p rows [j0-100, j0+228) (328x128B, XOR-swizzled) -> ONE barrier ->
// per wave 8 j-tiles x 18 MFMAs (acc chains independent). Stats from accs;
// h transpose via aliased LDS hbuf[64][136].
// ---------------------------------------------------------------------------
__global__ __launch_bounds__(256) void k_tcn(
    const unsigned short* __restrict__ p, const unsigned short* __restrict__ twb,
    const float* __restrict__ tb, unsigned short* __restrict__ hout,
    float* __restrict__ stats4)
{
    __shared__ unsigned short lds[328*64];   // 41984 B; reused as hbuf[64][136]

    const int bj = blockIdx.x, n = blockIdx.y;
    const int j0 = bj*128;
    const int tid = threadIdx.x;
    const int lane = tid & 63, ct = tid >> 6;
    const int lg = lane >> 4, lr = lane & 15;
    const int cA = ct*16 + lr;               // A-frag row (out channel)
    const int cbase = ct*16 + 4*lg;          // D row base

    // stage: p rows j0-100 .. j0+227 (p index offset +128 => +28)
    const unsigned short* psrc = p + ((size_t)n*PROWS + 28 + j0)*64;
    for (int e = tid; e < 2624; e += 256) {
        int row = e >> 3, q = e & 7;
        s8v v = *(const s8v*)&psrc[(size_t)row*64 + q*8];
        *(s8v*)&lds[row*64 + ((q ^ (row & 7)))*8] = v;
    }

    f32x4 acc[8];
    #pragma unroll
    for (int i = 0; i < 8; ++i) acc[i] = (f32x4){0.f,0.f,0.f,0.f};
    float tbc[4];
    #pragma unroll
    for (int r = 0; r < 4; ++r) tbc[r] = tb[cbase + r];

    __syncthreads();

    #pragma unroll
    for (int ks = 0; ks < 2; ++ks) {
        bf16x8 af[9];
        #pragma unroll
        for (int dt = 0; dt < 9; ++dt)
            af[dt] = *(const bf16x8*)&twb[((2*dt + ks)*64 + cA)*32 + 8*lg];
        #pragma unroll
        for (int jt = 0; jt < 8; ++jt) {
            #pragma unroll
            for (int dt = 0; dt < 9; ++dt) {
                int row = 16*jt + lr + 25*dt;            // [0, 328)
                bf16x8 b = *(const bf16x8*)&lds[row*64 + ((4*ks + lg) ^ (row & 7))*8];
                acc[jt] = __builtin_amdgcn_mfma_f32_16x16x32_bf16(af[dt], b, acc[jt], 0, 0, 0);
            }
        }
    }

    // stats partials (guard j<7500; pads give acc=0 there but bias must not count)
    float sacc[4] = {0,0,0,0}, qacc[4] = {0,0,0,0};
    #pragma unroll
    for (int jt = 0; jt < 8; ++jt) {
        int j = j0 + 16*jt + lr;
        if (j < 7500) {
            #pragma unroll
            for (int r = 0; r < 4; ++r) {
                float v = acc[jt][r] + tbc[r];
                sacc[r] += v; qacc[r] += v*v;
            }
        }
    }
    #pragma unroll
    for (int r = 0; r < 4; ++r) {
        float s = sacc[r], q = qacc[r];
        s += __shfl_xor(s, 1); s += __shfl_xor(s, 2);
        s += __shfl_xor(s, 4); s += __shfl_xor(s, 8);
        q += __shfl_xor(q, 1); q += __shfl_xor(q, 2);
        q += __shfl_xor(q, 4); q += __shfl_xor(q, 8);
        if (lr == 0) {
            float* dst = stats4 + (size_t)(n*59 + bj)*128;
            dst[cbase + r] = s;
            dst[64 + cbase + r] = q;
        }
    }

    // transpose epilogue: hbuf[c][j-j0] (stride 136), then coalesced s4v stores
    __syncthreads();               // all LDS reads done before overwrite
    #pragma unroll
    for (int jt = 0; jt < 8; ++jt)
        #pragma unroll
        for (int r = 0; r < 4; ++r)
            lds[(cbase + r)*136 + 16*jt + lr] = f2bf(acc[jt][r] + tbc[r]);
    __syncthreads();
    for (int e = tid; e < 2048; e += 256) {
        int row = e >> 5, c4 = (e & 31) << 2;
        int j = j0 + c4;
        if (j < 7500)
            *(s4v*)&hout[(size_t)(n*64 + row)*7500 + j] = *(const s4v*)&lds[row*136 + c4];
    }
}

// ---------------------------------------------------------------------------
// k_out: out = relu(bn2(h) + x) f32
// ---------------------------------------------------------------------------
__global__ __launch_bounds__(256) void k_out(
    const unsigned short* __restrict__ h, const float* __restrict__ x,
    const float* __restrict__ sb, float* __restrict__ out)
{
    int i4 = blockIdx.x * 256 + threadIdx.x;
    if (i4 >= NELEM/4) return;
    int c = ((i4*4) / TV) & 63;
    float s2 = sb[128 + c], b2 = sb[192 + c];
    s4v hv = *(const s4v*)&h[i4*4];
    float4 xv = ((const float4*)x)[i4];
    float4 o;
    o.x = fmaxf(fmaf(bf2f((unsigned short)hv[0]), s2, b2) + xv.x, 0.f);
    o.y = fmaxf(fmaf(bf2f((unsigned short)hv[1]), s2, b2) + xv.y, 0.f);
    o.z = fmaxf(fmaf(bf2f((unsigned short)hv[2]), s2, b2) + xv.z, 0.f);
    o.w = fmaxf(fmaf(bf2f((unsigned short)hv[3]), s2, b2) + xv.w, 0.f);
    ((float4*)out)[i4] = o;
}

// ---------------------------------------------------------------------------
extern "C" void kernel_launch(void* const* d_in, const int* in_sizes, int n_in,
                              void* d_out, int out_size, void* d_ws, size_t ws_size,
                              hipStream_t stream)
{
    const float* x      = (const float*)d_in[0];
    const float* A      = (const float*)d_in[1];
    const float* B      = (const float*)d_in[2];
    const float* lamda  = (const float*)d_in[3];
    const float* conv_w = (const float*)d_in[4];
    const float* conv_b = (const float*)d_in[5];
    const float* bn1_g  = (const float*)d_in[6];
    const float* bn1_b  = (const float*)d_in[7];
    const float* tcn_w  = (const float*)d_in[8];
    const float* tcn_b  = (const float*)d_in[9];
    const float* bn2_g  = (const float*)d_in[10];
    const float* bn2_b  = (const float*)d_in[11];

    unsigned short* g = (unsigned short*)d_ws;          // NELEM bf16
    unsigned short* p = g + NELEM;                      // 32*7788*64 bf16
    unsigned short* h = p + (size_t)N_*PROWS*64;        // NELEM bf16
    float* stats3 = (float*)(h + NELEM);                // 960*128
    float* stats4 = stats3 + 960*128;                   // 1888*128
    float* sb     = stats4 + 1888*128;                  // 256
    unsigned short* w2b = (unsigned short*)(sb + 256);  // 20480
    unsigned short* twb = w2b + 20480;                  // 36864

    k_prep<<<32, 256, 0, stream>>>(conv_w, tcn_w, w2b, twb);
    k_gcn<<<dim3(30, N_), 256, 0, stream>>>(x, A, B, lamda, w2b, conv_b, g, stats3);
    k_fin<<<64, 256, 0, stream>>>(stats3, 960, sb, bn1_g, bn1_b);
    k_bn1<<<PROWS, 256, 0, stream>>>(g, sb, p);
    k_tcn<<<dim3(59, N_), 256, 0, stream>>>(p, twb, tcn_b, h, stats4);
    k_fin<<<64, 256, 0, stream>>>(stats4, 1888, sb + 128, bn2_g, bn2_b);
    k_out<<<NELEM/4/256, 256, 0, stream>>>(h, x, sb, (float*)d_out);
}